// Round 10
// baseline (145.027 us; speedup 1.0000x reference)
//
#include <hip/hip_runtime.h>
#include <stdint.h>

#define S_LEN 4096
#define D_DIM 2048
#define NT 16
#define TD 128
#define KW 4
#define CTX 640
#define HID 256

typedef __bf16 bf16_t;
typedef __bf16 bf16x8 __attribute__((ext_vector_type(8)));
typedef __bf16 bf16x4 __attribute__((ext_vector_type(4)));
typedef float f32x4 __attribute__((ext_vector_type(4)));

// ---------------- Kernel 1: row stats + tile-sum partials (NO xn write; LN is
// recomputed inside k_mlp). partial[blk][d] = sum_{s in blk} (x-mu)*rstd  (no gamma/beta).
__global__ __launch_bounds__(256) void k_stats(const float* __restrict__ x,
                                               float* __restrict__ partial)
{
    __shared__ float wsum[4][2048];
    const int tid = threadIdx.x, lane = tid & 63, w = tid >> 6;
    const int blk = blockIdx.x;
    float cs[8][4];
#pragma unroll
    for (int j = 0; j < 8; ++j) { cs[j][0]=0.f; cs[j][1]=0.f; cs[j][2]=0.f; cs[j][3]=0.f; }
#pragma unroll
    for (int i = 0; i < 4; ++i) {
        const int r = blk*16 + w*4 + i;
        const float4* xr = (const float4*)(x + (size_t)r * D_DIM);
        float4 v[8]; float s = 0.f, ss = 0.f;
#pragma unroll
        for (int j = 0; j < 8; ++j) {
            v[j] = xr[j*64 + lane];
            s  += v[j].x + v[j].y + v[j].z + v[j].w;
            ss += v[j].x*v[j].x + v[j].y*v[j].y + v[j].z*v[j].z + v[j].w*v[j].w;
        }
#pragma unroll
        for (int off = 32; off; off >>= 1) { s += __shfl_xor(s, off); ss += __shfl_xor(ss, off); }
        const float mean = s * (1.f/2048.f);
        const float var  = ss * (1.f/2048.f) - mean*mean;
        const float rstd = rsqrtf(var + 1e-5f);
#pragma unroll
        for (int j = 0; j < 8; ++j) {
            cs[j][0] += (v[j].x - mean)*rstd;
            cs[j][1] += (v[j].y - mean)*rstd;
            cs[j][2] += (v[j].z - mean)*rstd;
            cs[j][3] += (v[j].w - mean)*rstd;
        }
    }
#pragma unroll
    for (int j = 0; j < 8; ++j) {
        float4 t4; t4.x=cs[j][0]; t4.y=cs[j][1]; t4.z=cs[j][2]; t4.w=cs[j][3];
        *(float4*)&wsum[w][(j*64+lane)*4] = t4;
    }
    __syncthreads();
#pragma unroll
    for (int p = 0; p < 2; ++p) {
        const int c4 = p*256 + tid;
        float4 a0 = *(const float4*)&wsum[0][c4*4];
        float4 a1 = *(const float4*)&wsum[1][c4*4];
        float4 a2 = *(const float4*)&wsum[2][c4*4];
        float4 a3 = *(const float4*)&wsum[3][c4*4];
        float4 r4; r4.x=a0.x+a1.x+a2.x+a3.x; r4.y=a0.y+a1.y+a2.y+a3.y;
        r4.z=a0.z+a1.z+a2.z+a3.z; r4.w=a0.w+a1.w+a2.w+a3.w;
        *(float4*)(partial + (size_t)blk*D_DIM + c4*4) = r4;
    }
}

// ---------------- Kernel 2a: partial[512][2048] -> partial2[64][2048]
__global__ __launch_bounds__(256) void k_red1(const float* __restrict__ partial,
                                              float* __restrict__ partial2) {
    const int g = blockIdx.x, tid = threadIdx.x;
#pragma unroll
    for (int p = 0; p < 2; ++p) {
        const int c4 = p*256 + tid;
        float4 s = {0.f,0.f,0.f,0.f};
#pragma unroll
        for (int r = 0; r < 8; ++r) {
            float4 v = *(const float4*)(partial + ((size_t)(g*8+r))*2048 + c4*4);
            s.x+=v.x; s.y+=v.y; s.z+=v.z; s.w+=v.w;
        }
        *(float4*)(partial2 + (size_t)g*2048 + c4*4) = s;
    }
}

// ---------------- Kernel 3a: reduce partial2 (+ gamma/beta) + q/k proj + l2norm
__global__ __launch_bounds__(256) void k_qk(const float* __restrict__ partial2,
        const float* __restrict__ gamma, const float* __restrict__ beta,
        const float* __restrict__ Wq, const float* __restrict__ bq,
        const float* __restrict__ Wk, const float* __restrict__ bk,
        float* __restrict__ qkbuf)
{
    __shared__ float red2[2][128];
    __shared__ float rrow[128];
    __shared__ float yrow[128];
    __shared__ float ssum[2];
    const int g = blockIdx.x;
    const int b = g >> 5, t = (g >> 1) & 15, which = g & 1;
    const float* W    = which ? Wk : Wq;
    const float* bias = which ? bk : bq;
    const int tid = threadIdx.x, lane = tid & 63, w = tid >> 6;
    {
        const int c = tid & 127, hh = tid >> 7;
        float s = 0.f;
#pragma unroll
        for (int r = 0; r < 16; ++r)
            s += partial2[(size_t)(b*32 + hh*16 + r)*2048 + t*128 + c];
        red2[hh][c] = s;
    }
    __syncthreads();
    if (tid < 128)
        rrow[tid] = gamma[t*128 + tid] * (red2[0][tid] + red2[1][tid]) * (1.f/4096.f)
                  + beta[t*128 + tid];
    __syncthreads();
    const int c0 = (lane & 15) * 8;
#pragma unroll
    for (int r = 0; r < 8; ++r) {
        const int d = r*16 + w*4 + (lane >> 4);
        const float4 w0 = *(const float4*)(W + d*128 + c0);
        const float4 w1 = *(const float4*)(W + d*128 + c0 + 4);
        float acc = w0.x*rrow[c0]   + w0.y*rrow[c0+1] + w0.z*rrow[c0+2] + w0.w*rrow[c0+3]
                  + w1.x*rrow[c0+4] + w1.y*rrow[c0+5] + w1.z*rrow[c0+6] + w1.w*rrow[c0+7];
#pragma unroll
        for (int off = 1; off <= 8; off <<= 1) acc += __shfl_xor(acc, off);
        if ((lane & 15) == 0) yrow[d] = acc + bias[d];
    }
    __syncthreads();
    if (tid < 128) {
        float v = yrow[tid];
        float sq = v * v;
#pragma unroll
        for (int off = 32; off; off >>= 1) sq += __shfl_xor(sq, off);
        if (lane == 0) ssum[tid >> 6] = sq;
    }
    __syncthreads();
    if (tid < 128) {
        const float rn = 1.f / fmaxf(sqrtf(ssum[0] + ssum[1]), 1e-12f);
        qkbuf[(which*32 + b*16 + t)*128 + tid] = yrow[tid] * rn;
    }
}

// ---------------- Kernel 3b: scores + top-4 -> routes [B][T][K]
__global__ __launch_bounds__(256) void k_score(const float* __restrict__ qkbuf,
                                               int* __restrict__ routes)
{
    __shared__ float qk_s[8192];
    __shared__ float sc[2][16][16];
    const int tid = threadIdx.x;
    for (int i = tid; i < 2048; i += 256)
        *(float4*)&qk_s[i*4] = *(const float4*)(qkbuf + i*4);
    __syncthreads();
#pragma unroll
    for (int p = 0; p < 2; ++p) {
        const int e = p*256 + tid;
        const int b = e >> 8, t = (e >> 4) & 15, u = e & 15;
        const float4* qr = (const float4*)&qk_s[(b*16 + t)*128];
        const float4* kr = (const float4*)&qk_s[(32 + b*16 + u)*128];
        float s = 0.f;
#pragma unroll
        for (int c = 0; c < 32; ++c) {
            float4 a = qr[c], bb = kr[c];
            s += a.x*bb.x + a.y*bb.y + a.z*bb.z + a.w*bb.w;
        }
        sc[b][t][u] = (u == t) ? -1e9f : s;
    }
    __syncthreads();
    if (tid < 32) {
        const int b = tid >> 4, t = tid & 15;
        unsigned taken = 0;
        for (int kk = 0; kk < 4; ++kk) {
            float bv = -3.0e38f; int bu = 0;
            for (int u = 0; u < 16; ++u) {
                if ((taken >> u) & 1u) continue;
                const float v = sc[b][t][u];
                if (v > bv) { bv = v; bu = u; }   // strict > = lax.top_k tie-break
            }
            taken |= (1u << bu);
            routes[(b*16 + t)*4 + kk] = bu;
        }
    }
}

// ---------------- Kernel 4: W1/W2 -> bf16 k-blocked layouts for direct frag loads.
// W1c[kb(20)][n(256)][kw(32)]; W2c[kb(8)][n(128)][kw(32)].
// Fragment load = 64 lanes x 16B = contiguous 1KB (16 n-rows x 64B).
__global__ void k_prep(const float* __restrict__ W1, const float* __restrict__ W2,
                       bf16_t* __restrict__ W1c, bf16_t* __restrict__ W2c) {
    const int g = blockIdx.x * 256 + threadIdx.x;
    if (g < 20*256*32) {
        const int kb = g >> 13, rem = g & 8191, n = rem >> 5, kw = rem & 31;
        W1c[g] = (bf16_t)W1[n*CTX + kb*32 + kw];
    } else if (g < 20*256*32 + 8*128*32) {
        const int gg = g - 20*256*32;
        const int kb = gg >> 12, n = (gg >> 5) & 127, kw = gg & 31;
        W2c[gg] = (bf16_t)W2[n*HID + kb*32 + kw];
    }
}

// ---------------- Kernel 5: fused LN + gather + MLP + residual, BARRIER-FREE GEMM1.
// 512 blocks x 512 threads (8 waves). BM=256 rows (16 s x 16 t).
// Stage 1 (LN): each wave LNs 2 x-rows (f32 from global) -> xnL[16][2048] bf16 in LDS,
//   swizzled: 16B-chunk phys = logical ^ (tile&7), tile = d>>7. One-time write.
// GEMM1 (no barriers, no staging): per (ks,kk): af[4] = W1c fragments DIRECT from
//   global (1KB coalesced, L2-hot); bfr[8] = per-lane gather ds_read_b128 from xnL
//   (source tile via srcT, <=2-way banks); 32 MFMA. Compiler/HW overlap freely.
// GEMM2: h through hL (64KB, aliases dead xnL) in 2 phases; W2 frags direct from L2.
__global__ __launch_bounds__(512, 1) void k_mlp(
    const float* __restrict__ x,
    const float* __restrict__ gamma, const float* __restrict__ beta,
    const bf16_t* __restrict__ W1c, const bf16_t* __restrict__ W2c,
    const float* __restrict__ b1, const float* __restrict__ b2,
    const int* __restrict__ routes, float* __restrict__ out)
{
    __shared__ char lds[65856];              // [0,64K): xnL then hL; srcT @64K
    int* srcT = (int*)(lds + 65536);

    const int tid = threadIdx.x, lane = tid & 63, w = tid >> 6;
    const int blk = blockIdx.x;
    const int b  = blk >> 8;
    const int s0 = (blk & 255) * 16;

    if (tid < 80) {
        const int t = tid / 5, j = tid % 5;
        srcT[tid] = (j == 0) ? t : routes[(b*NT + t)*KW + (j-1)];
    }
    __syncthreads();

    // per-lane gather constants: lane's t = lane&15
    int r_p[5], r_q[5];
#pragma unroll
    for (int j = 0; j < 5; ++j) {
        const int sj = srcT[(lane & 15)*5 + j];
        r_p[j] = sj * 256;                   // byte offset of source tile in xnL row
        r_q[j] = sj & 7;                     // swizzle key
    }

    // ---- Stage 1: LayerNorm 16 rows -> xnL (bf16, swizzled) ----
    const int swz = (lane >> 2) & 7;         // writer tile&7 = (lane>>2)&7
#pragma unroll
    for (int i = 0; i < 2; ++i) {
        const int sl = w*2 + i;
        const float4* xr = (const float4*)(x + ((size_t)(b*S_LEN + s0 + sl))*D_DIM);
        float4 v[8]; float s = 0.f, ss = 0.f;
#pragma unroll
        for (int j = 0; j < 8; ++j) {
            v[j] = xr[lane*8 + j];            // d = lane*32 + j*4 (lane-contiguous)
            s  += v[j].x + v[j].y + v[j].z + v[j].w;
            ss += v[j].x*v[j].x + v[j].y*v[j].y + v[j].z*v[j].z + v[j].w*v[j].w;
        }
#pragma unroll
        for (int off = 32; off; off >>= 1) { s += __shfl_xor(s, off); ss += __shfl_xor(ss, off); }
        const float mean = s * (1.f/2048.f);
        const float var  = ss * (1.f/2048.f) - mean*mean;
        const float rstd = rsqrtf(var + 1e-5f);
        const float4* g4 = (const float4*)gamma;
        const float4* e4 = (const float4*)beta;
#pragma unroll
        for (int q = 0; q < 4; ++q) {
            const float4 va = v[2*q], vb = v[2*q+1];
            const float4 ga = g4[lane*8 + 2*q], gb = g4[lane*8 + 2*q + 1];
            const float4 ea = e4[lane*8 + 2*q], eb = e4[lane*8 + 2*q + 1];
            bf16x8 o;
            o[0] = (bf16_t)((va.x - mean)*rstd*ga.x + ea.x);
            o[1] = (bf16_t)((va.y - mean)*rstd*ga.y + ea.y);
            o[2] = (bf16_t)((va.z - mean)*rstd*ga.z + ea.z);
            o[3] = (bf16_t)((va.w - mean)*rstd*ga.w + ea.w);
            o[4] = (bf16_t)((vb.x - mean)*rstd*gb.x + eb.x);
            o[5] = (bf16_t)((vb.y - mean)*rstd*gb.y + eb.y);
            o[6] = (bf16_t)((vb.z - mean)*rstd*gb.z + eb.z);
            o[7] = (bf16_t)((vb.w - mean)*rstd*gb.w + eb.w);
            const int chunk = (lane*4 + q) ^ swz;
            *(bf16x8*)(lds + sl*4096 + chunk*16) = o;
        }
    }
    __syncthreads();

    // ---- GEMM1: h^T = W1 x comb, barrier-free ----
    const int wc = w & 3, wr = w >> 2;
    const int nbase = wc * 64;
    const int l15 = lane & 15;
    const int khi = lane >> 4;                // 0..3

    f32x4 acc[4][8];
#pragma unroll
    for (int i = 0; i < 4; ++i)
#pragma unroll
        for (int j = 0; j < 8; ++j) acc[i][j] = (f32x4){0.f,0.f,0.f,0.f};

#pragma unroll
    for (int ks = 0; ks < 10; ++ks) {
#pragma unroll
        for (int kk = 0; kk < 2; ++kk) {
            bf16x8 af[4], bfr[8];
            const bf16_t* wp = W1c + (ks*2 + kk)*8192 + khi*8;
#pragma unroll
            for (int nf = 0; nf < 4; ++nf)
                af[nf] = *(const bf16x8*)(wp + (nbase + nf*16 + l15)*32);
            const int c = (ks & 1)*8 + kk*4 + khi;      // logical 16B-chunk in tile
            const int coff = ((c ^ r_q[ks >> 1]) << 4) + r_p[ks >> 1];
#pragma unroll
            for (int mf = 0; mf < 8; ++mf)
                bfr[mf] = *(const bf16x8*)(lds + (wr*8 + mf)*4096 + coff);
#pragma unroll
            for (int nf = 0; nf < 4; ++nf)
#pragma unroll
                for (int mf = 0; mf < 8; ++mf)
                    acc[nf][mf] = __builtin_amdgcn_mfma_f32_16x16x32_bf16(
                        af[nf], bfr[mf], acc[nf][mf], 0, 0, 0);
        }
    }

    // ---- epilogue 1: bias + gelu -> packed bf16 regs ----
    bf16x4 hreg[4][8];
#pragma unroll
    for (int nf = 0; nf < 4; ++nf) {
        const int k0 = nbase + nf*16 + khi*4;
        const float4 b1v = *(const float4*)(b1 + k0);
#pragma unroll
        for (int mf = 0; mf < 8; ++mf) {
#pragma unroll
            for (int r = 0; r < 4; ++r) {
                const float z = acc[nf][mf][r] + ((const float*)&b1v)[r];
                const float uu = z + 0.044715f * z * z * z;
                const float gl = z / (1.f + __expf(-1.5957691216f * uu));
                hreg[nf][mf][r] = (bf16_t)gl;
            }
        }
    }

    __syncthreads();   // all xnL reads retired before hL overwrites it

    char* hA = lds;    // [256 m][128 k] bf16, 64KB, phased over hid-halves

    // phase A: waves wc<2 write h cols 0..127
    if (wc < 2) {
#pragma unroll
        for (int nf = 0; nf < 4; ++nf) {
            const int kA2 = (nbase + nf*16 + khi*4) * 2;
#pragma unroll
            for (int mf = 0; mf < 8; ++mf) {
                const int m = wr*128 + mf*16 + l15;
                *(bf16x4*)(hA + m*256 + (kA2 ^ ((m & 7) << 4))) = hreg[nf][mf];
            }
        }
    }
    __syncthreads();

    // ---- GEMM2: out = h @ W2^T (W2 frags direct from L2) ----
    const int wn = w & 1, wm = w >> 1;
    const int n2b = wn*64, m2b = wm*64;
    f32x4 acc2[4][4];
#pragma unroll
    for (int i = 0; i < 4; ++i)
#pragma unroll
        for (int j = 0; j < 4; ++j) acc2[i][j] = (f32x4){0.f,0.f,0.f,0.f};

#pragma unroll
    for (int kph = 0; kph < 2; ++kph) {
        if (kph == 1) {
            __syncthreads();
            if (wc >= 2) {     // phase B: waves wc>=2 write h cols 128..255
#pragma unroll
                for (int nf = 0; nf < 4; ++nf) {
                    const int kA2 = ((nbase - 128) + nf*16 + khi*4) * 2;
#pragma unroll
                    for (int mf = 0; mf < 8; ++mf) {
                        const int m = wr*128 + mf*16 + l15;
                        *(bf16x4*)(hA + m*256 + (kA2 ^ ((m & 7) << 4))) = hreg[nf][mf];
                    }
                }
            }
            __syncthreads();
        }
#pragma unroll
        for (int ksl = 0; ksl < 2; ++ksl) {
#pragma unroll
            for (int kk = 0; kk < 2; ++kk) {
                const int kbH = (ksl*64 + kk*32 + khi*8) * 2;
                bf16x8 ah[4], bw[4];
#pragma unroll
                for (int mf2 = 0; mf2 < 4; ++mf2) {
                    const int m = m2b + mf2*16 + l15;
                    ah[mf2] = *(const bf16x8*)(hA + m*256 + (kbH ^ ((m & 7) << 4)));
                }
                const bf16_t* w2p = W2c + (kph*4 + ksl*2 + kk)*4096 + khi*8;
#pragma unroll
                for (int nf2 = 0; nf2 < 4; ++nf2)
                    bw[nf2] = *(const bf16x8*)(w2p + (n2b + nf2*16 + l15)*32);
#pragma unroll
                for (int nf2 = 0; nf2 < 4; ++nf2)
#pragma unroll
                    for (int mf2 = 0; mf2 < 4; ++mf2)
                        acc2[nf2][mf2] = __builtin_amdgcn_mfma_f32_16x16x32_bf16(
                            ah[mf2], bw[nf2], acc2[nf2][mf2], 0, 0, 0);
            }
        }
    }

    // ---- epilogue 2: + b2 + residual x ----
#pragma unroll
    for (int nf2 = 0; nf2 < 4; ++nf2) {
        const int n2 = n2b + nf2*16 + l15;
        const float b2v = b2[n2];
#pragma unroll
        for (int mf2 = 0; mf2 < 4; ++mf2) {
            const int mb = m2b + mf2*16 + khi*4;
#pragma unroll
            for (int r = 0; r < 4; ++r) {
                const int m = mb + r;
                const int s = s0 + (m >> 4);
                const int t = m & 15;
                const size_t o = ((size_t)(b*S_LEN + s))*D_DIM + t*TD + n2;
                out[o] = x[o] + acc2[nf2][mf2][r] + b2v;
            }
        }
    }
}

extern "C" void kernel_launch(void* const* d_in, const int* in_sizes, int n_in,
                              void* d_out, int out_size, void* d_ws, size_t ws_size,
                              hipStream_t stream) {
    const float* x     = (const float*)d_in[0];
    const float* gamma = (const float*)d_in[1];
    const float* beta  = (const float*)d_in[2];
    const float* Wq    = (const float*)d_in[3];
    const float* bq    = (const float*)d_in[4];
    const float* Wk    = (const float*)d_in[5];
    const float* bk    = (const float*)d_in[6];
    const float* W1    = (const float*)d_in[7];
    const float* b1    = (const float*)d_in[8];
    const float* W2    = (const float*)d_in[9];
    const float* b2    = (const float*)d_in[10];
    float* out = (float*)d_out;

    char* ws = (char*)d_ws;
    float*  partial  = (float*) ws;                   // 4,194,304 B [512][2048]
    float*  partial2 = (float*) (ws + 4194304);       //   524,288 B [64][2048]
    float*  qkbuf    = (float*) (ws + 4718592);       //    32,768 B
    int*    routes   = (int*)   (ws + 4751360);       //       512 B
    bf16_t* W1c      = (bf16_t*)(ws + 4751872);       //   327,680 B
    bf16_t* W2c      = (bf16_t*)(ws + 5079552);       //    65,536 B

    k_prep<<<768, 256, 0, stream>>>(W1, W2, W1c, W2c);
    k_stats<<<512, 256, 0, stream>>>(x, partial);
    k_red1<<<64, 256, 0, stream>>>(partial, partial2);
    k_qk<<<64, 256, 0, stream>>>(partial2, gamma, beta, Wq, bq, Wk, bk, qkbuf);
    k_score<<<1, 256, 0, stream>>>(qkbuf, routes);
    k_mlp<<<512, 512, 0, stream>>>(x, gamma, beta, W1c, W2c, b1, b2, routes, out);
}

// Round 11
// 126.355 us; speedup vs baseline: 1.1478x; 1.1478x over previous
//
#include <hip/hip_runtime.h>
#include <stdint.h>

#define S_LEN 4096
#define D_DIM 2048
#define NT 16
#define TD 128
#define KW 4
#define CTX 640
#define HID 256

typedef __bf16 bf16_t;
typedef __bf16 bf16x8 __attribute__((ext_vector_type(8)));
typedef __bf16 bf16x4 __attribute__((ext_vector_type(4)));
typedef float f32x4 __attribute__((ext_vector_type(4)));
typedef unsigned int u32;
typedef u32 __attribute__((address_space(1))) gu32;
typedef u32 __attribute__((address_space(3))) lu32;

__device__ __forceinline__ void gload_lds16(const void* g, void* l) {
    __builtin_amdgcn_global_load_lds((const gu32*)g, (lu32*)l, 16, 0, 0);
}

// ---------------- Kernel 1: row stats + tile-sum partials (no xn write).
// partial[blk][d] = sum_{s in blk} (x-mu)*rstd   (gamma/beta applied in k_qk).
__global__ __launch_bounds__(256) void k_stats(const float* __restrict__ x,
                                               float* __restrict__ partial)
{
    __shared__ float wsum[4][2048];
    const int tid = threadIdx.x, lane = tid & 63, w = tid >> 6;
    const int blk = blockIdx.x;
    float cs[8][4];
#pragma unroll
    for (int j = 0; j < 8; ++j) { cs[j][0]=0.f; cs[j][1]=0.f; cs[j][2]=0.f; cs[j][3]=0.f; }
#pragma unroll
    for (int i = 0; i < 4; ++i) {
        const int r = blk*16 + w*4 + i;
        const float4* xr = (const float4*)(x + (size_t)r * D_DIM);
        float4 v[8]; float s = 0.f, ss = 0.f;
#pragma unroll
        for (int j = 0; j < 8; ++j) {
            v[j] = xr[j*64 + lane];
            s  += v[j].x + v[j].y + v[j].z + v[j].w;
            ss += v[j].x*v[j].x + v[j].y*v[j].y + v[j].z*v[j].z + v[j].w*v[j].w;
        }
#pragma unroll
        for (int off = 32; off; off >>= 1) { s += __shfl_xor(s, off); ss += __shfl_xor(ss, off); }
        const float mean = s * (1.f/2048.f);
        const float var  = ss * (1.f/2048.f) - mean*mean;
        const float rstd = rsqrtf(var + 1e-5f);
#pragma unroll
        for (int j = 0; j < 8; ++j) {
            cs[j][0] += (v[j].x - mean)*rstd;
            cs[j][1] += (v[j].y - mean)*rstd;
            cs[j][2] += (v[j].z - mean)*rstd;
            cs[j][3] += (v[j].w - mean)*rstd;
        }
    }
#pragma unroll
    for (int j = 0; j < 8; ++j) {
        float4 t4; t4.x=cs[j][0]; t4.y=cs[j][1]; t4.z=cs[j][2]; t4.w=cs[j][3];
        *(float4*)&wsum[w][(j*64+lane)*4] = t4;
    }
    __syncthreads();
#pragma unroll
    for (int p = 0; p < 2; ++p) {
        const int c4 = p*256 + tid;
        float4 a0 = *(const float4*)&wsum[0][c4*4];
        float4 a1 = *(const float4*)&wsum[1][c4*4];
        float4 a2 = *(const float4*)&wsum[2][c4*4];
        float4 a3 = *(const float4*)&wsum[3][c4*4];
        float4 r4; r4.x=a0.x+a1.x+a2.x+a3.x; r4.y=a0.y+a1.y+a2.y+a3.y;
        r4.z=a0.z+a1.z+a2.z+a3.z; r4.w=a0.w+a1.w+a2.w+a3.w;
        *(float4*)(partial + (size_t)blk*D_DIM + c4*4) = r4;
    }
}

// ---------------- Kernel 2a: partial[512][2048] -> partial2[64][2048]
__global__ __launch_bounds__(256) void k_red1(const float* __restrict__ partial,
                                              float* __restrict__ partial2) {
    const int g = blockIdx.x, tid = threadIdx.x;
#pragma unroll
    for (int p = 0; p < 2; ++p) {
        const int c4 = p*256 + tid;
        float4 s = {0.f,0.f,0.f,0.f};
#pragma unroll
        for (int r = 0; r < 8; ++r) {
            float4 v = *(const float4*)(partial + ((size_t)(g*8+r))*2048 + c4*4);
            s.x+=v.x; s.y+=v.y; s.z+=v.z; s.w+=v.w;
        }
        *(float4*)(partial2 + (size_t)g*2048 + c4*4) = s;
    }
}

// ---------------- Kernel 3a: reduce partial2 (+gamma/beta) + q/k proj + l2norm
__global__ __launch_bounds__(256) void k_qk(const float* __restrict__ partial2,
        const float* __restrict__ gamma, const float* __restrict__ beta,
        const float* __restrict__ Wq, const float* __restrict__ bq,
        const float* __restrict__ Wk, const float* __restrict__ bk,
        float* __restrict__ qkbuf)
{
    __shared__ float red2[2][128];
    __shared__ float rrow[128];
    __shared__ float yrow[128];
    __shared__ float ssum[2];
    const int g = blockIdx.x;
    const int b = g >> 5, t = (g >> 1) & 15, which = g & 1;
    const float* W    = which ? Wk : Wq;
    const float* bias = which ? bk : bq;
    const int tid = threadIdx.x, lane = tid & 63, w = tid >> 6;
    {
        const int c = tid & 127, hh = tid >> 7;
        float s = 0.f;
#pragma unroll
        for (int r = 0; r < 16; ++r)
            s += partial2[(size_t)(b*32 + hh*16 + r)*2048 + t*128 + c];
        red2[hh][c] = s;
    }
    __syncthreads();
    if (tid < 128)
        rrow[tid] = gamma[t*128 + tid] * (red2[0][tid] + red2[1][tid]) * (1.f/4096.f)
                  + beta[t*128 + tid];
    __syncthreads();
    const int c0 = (lane & 15) * 8;
#pragma unroll
    for (int r = 0; r < 8; ++r) {
        const int d = r*16 + w*4 + (lane >> 4);
        const float4 w0 = *(const float4*)(W + d*128 + c0);
        const float4 w1 = *(const float4*)(W + d*128 + c0 + 4);
        float acc = w0.x*rrow[c0]   + w0.y*rrow[c0+1] + w0.z*rrow[c0+2] + w0.w*rrow[c0+3]
                  + w1.x*rrow[c0+4] + w1.y*rrow[c0+5] + w1.z*rrow[c0+6] + w1.w*rrow[c0+7];
#pragma unroll
        for (int off = 1; off <= 8; off <<= 1) acc += __shfl_xor(acc, off);
        if ((lane & 15) == 0) yrow[d] = acc + bias[d];
    }
    __syncthreads();
    if (tid < 128) {
        float v = yrow[tid];
        float sq = v * v;
#pragma unroll
        for (int off = 32; off; off >>= 1) sq += __shfl_xor(sq, off);
        if (lane == 0) ssum[tid >> 6] = sq;
    }
    __syncthreads();
    if (tid < 128) {
        const float rn = 1.f / fmaxf(sqrtf(ssum[0] + ssum[1]), 1e-12f);
        qkbuf[(which*32 + b*16 + t)*128 + tid] = yrow[tid] * rn;
    }
}

// ---------------- Kernel 3b: scores + top-4 -> routes [B][T][K]
__global__ __launch_bounds__(256) void k_score(const float* __restrict__ qkbuf,
                                               int* __restrict__ routes)
{
    __shared__ float qk_s[8192];
    __shared__ float sc[2][16][16];
    const int tid = threadIdx.x;
    for (int i = tid; i < 2048; i += 256)
        *(float4*)&qk_s[i*4] = *(const float4*)(qkbuf + i*4);
    __syncthreads();
#pragma unroll
    for (int p = 0; p < 2; ++p) {
        const int e = p*256 + tid;
        const int b = e >> 8, t = (e >> 4) & 15, u = e & 15;
        const float4* qr = (const float4*)&qk_s[(b*16 + t)*128];
        const float4* kr = (const float4*)&qk_s[(32 + b*16 + u)*128];
        float s = 0.f;
#pragma unroll
        for (int c = 0; c < 32; ++c) {
            float4 a = qr[c], bb = kr[c];
            s += a.x*bb.x + a.y*bb.y + a.z*bb.z + a.w*bb.w;
        }
        sc[b][t][u] = (u == t) ? -1e9f : s;
    }
    __syncthreads();
    if (tid < 32) {
        const int b = tid >> 4, t = tid & 15;
        unsigned taken = 0;
        for (int kk = 0; kk < 4; ++kk) {
            float bv = -3.0e38f; int bu = 0;
            for (int u = 0; u < 16; ++u) {
                if ((taken >> u) & 1u) continue;
                const float v = sc[b][t][u];
                if (v > bv) { bv = v; bu = u; }   // strict > = lax.top_k tie-break
            }
            taken |= (1u << bu);
            routes[(b*16 + t)*4 + kk] = bu;
        }
    }
}

// ---------------- Kernel 4: pre-tile + pre-swizzle W1/W2 into bf16 LDS images
// LDS slot L holds logical element at (byte L) ^ ((row&7)<<4)  [rows of 128B]
__global__ void k_prep(const float* __restrict__ W1, const float* __restrict__ W2,
                       bf16_t* __restrict__ W1t, bf16_t* __restrict__ W2t) {
    const int g = blockIdx.x * 256 + threadIdx.x;
    if (g < 10*256*64) {
        const int ks = g >> 14, rem = g & 16383, n = rem >> 6, kk = rem & 63;
        const int kkl = ((kk << 1) ^ ((n & 7) << 4)) >> 1;
        W1t[g] = (bf16_t)W1[n*CTX + ks*64 + kkl];
    } else if (g < 10*256*64 + 4*128*64) {
        const int gg = g - 10*256*64;
        const int ks = gg >> 13, rem = gg & 8191, n = rem >> 6, kk = rem & 63;
        const int kkl = ((kk << 1) ^ ((n & 7) << 4)) >> 1;
        W2t[gg] = (bf16_t)W2[n*HID + ks*64 + kkl];
    }
}

// ---------------- Kernel 5: fused LN + gather + MLP + residual.
// 512 blocks x 512 threads (8 waves). Output rows m = t*16 + s (T-MAJOR):
//   B-fragment lanes then have t wave-uniform (u = srcT[t][j] broadcast) and
//   s = lane&15 -> per-lane rows, chunk-XOR c^(s&7) -> ZERO extra bank conflicts
//   independent of routes (round-10 fix).
// LDS: xnL [16 s][16 u][16 chunks of 16B] 64KB @0 (chunk stored at c^(s&7));
//   W1 dbuf 2x32KB @64K (gload_lds, counted vmcnt(4), 2 raw barriers/ks);
//   GEMM2: hA 64KB @0 (aliases xnL), W2 64KB @64K; srcT @128K.
__global__ __launch_bounds__(512, 1) void k_mlp(
    const float* __restrict__ x,
    const float* __restrict__ gamma, const float* __restrict__ beta,
    const bf16_t* __restrict__ W1t, const bf16_t* __restrict__ W2t,
    const float* __restrict__ b1, const float* __restrict__ b2,
    const int* __restrict__ routes, float* __restrict__ out)
{
    __shared__ char lds[131392];
    int* srcT = (int*)(lds + 131072);

    const int tid = threadIdx.x, lane = tid & 63, w = tid >> 6;
    const int blk = blockIdx.x;
    const int b  = blk >> 8;
    const int s0 = (blk & 255) * 16;

    if (tid < 80) {
        const int t = tid / 5, j = tid % 5;
        srcT[tid] = (j == 0) ? t : routes[(b*NT + t)*KW + (j-1)];
    }

    // ---- Stage 1: LayerNorm 16 rows -> xnL (bf16). Writer lane owns global
    // chunks q*64+lane (q=0..3): groups = lane&7, uniform -> conflict-free.
    __syncthreads();   // srcT visible (also orders nothing else yet)
#pragma unroll
    for (int i = 0; i < 2; ++i) {
        const int sl = w*2 + i;
        const float4* xr = (const float4*)(x + ((size_t)(b*S_LEN + s0 + sl))*D_DIM);
        float4 v[8]; float s = 0.f, ss = 0.f;
#pragma unroll
        for (int q = 0; q < 4; ++q) {
#pragma unroll
            for (int p = 0; p < 2; ++p) {
                float4 vv = xr[(q*64 + lane)*2 + p];
                v[q*2+p] = vv;
                s  += vv.x + vv.y + vv.z + vv.w;
                ss += vv.x*vv.x + vv.y*vv.y + vv.z*vv.z + vv.w*vv.w;
            }
        }
#pragma unroll
        for (int off = 32; off; off >>= 1) { s += __shfl_xor(s, off); ss += __shfl_xor(ss, off); }
        const float mean = s * (1.f/2048.f);
        const float var  = ss * (1.f/2048.f) - mean*mean;
        const float rstd = rsqrtf(var + 1e-5f);
        const float4* g4 = (const float4*)gamma;
        const float4* e4 = (const float4*)beta;
#pragma unroll
        for (int q = 0; q < 4; ++q) {
            const int gch = q*64 + lane;          // global 16B-chunk 0..255
            const float4 va = v[q*2], vb = v[q*2+1];
            const float4 ga = g4[gch*2], gb = g4[gch*2+1];
            const float4 ea = e4[gch*2], eb = e4[gch*2+1];
            bf16x8 o;
            o[0] = (bf16_t)((va.x - mean)*rstd*ga.x + ea.x);
            o[1] = (bf16_t)((va.y - mean)*rstd*ga.y + ea.y);
            o[2] = (bf16_t)((va.z - mean)*rstd*ga.z + ea.z);
            o[3] = (bf16_t)((va.w - mean)*rstd*ga.w + ea.w);
            o[4] = (bf16_t)((vb.x - mean)*rstd*gb.x + eb.x);
            o[5] = (bf16_t)((vb.y - mean)*rstd*gb.y + eb.y);
            o[6] = (bf16_t)((vb.z - mean)*rstd*gb.z + eb.z);
            o[7] = (bf16_t)((vb.w - mean)*rstd*gb.w + eb.w);
            const int u  = gch >> 4;              // source tile
            const int cw = gch & 15;              // chunk within tile
            *(bf16x8*)(lds + sl*4096 + u*256 + ((cw ^ (sl & 7)) << 4)) = o;
        }
    }

    const int wc = w & 3, wr = w >> 2;
    const int nbase = wc * 64;
    const int l15 = lane & 15;
    const int khi = lane >> 4;
    const int kb0 = khi * 16;                     // byte offset of khi's 8 elems
    const int cswz = (l15 & 7) << 4;              // reader chunk-XOR

    f32x4 acc[4][8];
#pragma unroll
    for (int i = 0; i < 4; ++i)
#pragma unroll
        for (int j = 0; j < 8; ++j) acc[i][j] = (f32x4){0.f,0.f,0.f,0.f};

    // prologue: stage W1(0) into buf0 @64K
    {
        const bf16_t* w1g = W1t + lane*8;
#pragma unroll
        for (int it = 0; it < 4; ++it)
            gload_lds16(w1g + (it*8 + w)*512, lds + 65536 + (it*8 + w)*1024);
    }
    __syncthreads();   // xnL fully written before any bfr read

    for (int ks = 0; ks < 10; ++ks) {
        const char* wb = lds + 65536 + (ks & 1) * 32768;
        char* nb = lds + 65536 + ((ks + 1) & 1) * 32768;
        if (ks < 9) {
            const bf16_t* w1g = W1t + (ks + 1)*16384 + lane*8;
#pragma unroll
            for (int it = 0; it < 4; ++it)
                gload_lds16(w1g + (it*8 + w)*512, nb + (it*8 + w)*1024);
            asm volatile("s_waitcnt vmcnt(4)" ::: "memory");
        } else {
            asm volatile("s_waitcnt vmcnt(0)" ::: "memory");
        }
        __builtin_amdgcn_s_barrier();

        int us[8];
#pragma unroll
        for (int mf = 0; mf < 8; ++mf)
            us[mf] = srcT[(wr*8 + mf)*5 + (ks >> 1)];   // wave-uniform broadcast

#pragma unroll
        for (int kk = 0; kk < 2; ++kk) {
            const int kb = (kk*32)*2 + kb0;             // W1t byte offset in row
            const int c  = (ks & 1)*8 + kk*4 + khi;     // xnL chunk within tile
            const int co = ((c << 4) ^ cswz);
            bf16x8 af[4], bfr[8];
#pragma unroll
            for (int nf = 0; nf < 4; ++nf) {
                const int n = nbase + nf*16 + l15;
                af[nf] = *(const bf16x8*)(wb + n*128 + (kb ^ ((n & 7) << 4)));
            }
#pragma unroll
            for (int mf = 0; mf < 8; ++mf)
                bfr[mf] = *(const bf16x8*)(lds + l15*4096 + us[mf]*256 + co);
#pragma unroll
            for (int nf = 0; nf < 4; ++nf)
#pragma unroll
                for (int mf = 0; mf < 8; ++mf)
                    acc[nf][mf] = __builtin_amdgcn_mfma_f32_16x16x32_bf16(
                        af[nf], bfr[mf], acc[nf][mf], 0, 0, 0);
        }
        asm volatile("s_waitcnt lgkmcnt(0)" ::: "memory");
        __builtin_amdgcn_s_barrier();
    }

    // ---- epilogue 1: bias + gelu -> packed bf16 regs ----
    bf16x4 hreg[4][8];
#pragma unroll
    for (int nf = 0; nf < 4; ++nf) {
        const int k0 = nbase + nf*16 + khi*4;
        const float4 b1v = *(const float4*)(b1 + k0);
#pragma unroll
        for (int mf = 0; mf < 8; ++mf) {
#pragma unroll
            for (int r = 0; r < 4; ++r) {
                const float z = acc[nf][mf][r] + ((const float*)&b1v)[r];
                const float uu = z + 0.044715f * z * z * z;
                const float gl = z / (1.f + __expf(-1.5957691216f * uu));
                hreg[nf][mf][r] = (bf16_t)gl;
            }
        }
    }

    // stage ALL of W2 (64KB) into [64K,128K) — W1 dbuf dead after final barrier
#pragma unroll
    for (int it = 0; it < 8; ++it) {
        const int q = it*8 + w;
        gload_lds16(W2t + q*512 + lane*8, lds + 65536 + q*1024);
    }

    char* hA = lds;   // [256 m][128 k] bf16, 64KB (phased over hid-halves)

    // phase A: waves wc<2 write h cols 0..127 (xnL dead: final K-loop barrier passed)
    if (wc < 2) {
#pragma unroll
        for (int nf = 0; nf < 4; ++nf) {
            const int kA2 = (nbase + nf*16 + khi*4) * 2;
#pragma unroll
            for (int mf = 0; mf < 8; ++mf) {
                const int m = wr*128 + mf*16 + l15;
                *(bf16x4*)(hA + m*256 + (kA2 ^ ((m & 7) << 4))) = hreg[nf][mf];
            }
        }
    }
    asm volatile("s_waitcnt vmcnt(0)" ::: "memory");
    __syncthreads();

    // ---- GEMM2: out = h @ W2^T, M=256 (wm), N=128 (wn), K=256 in 2 phases ----
    const int wn = w & 1, wm = w >> 1;
    const int n2b = wn*64, m2b = wm*64;
    f32x4 acc2[4][4];
#pragma unroll
    for (int i = 0; i < 4; ++i)
#pragma unroll
        for (int j = 0; j < 4; ++j) acc2[i][j] = (f32x4){0.f,0.f,0.f,0.f};

#pragma unroll
    for (int kph = 0; kph < 2; ++kph) {
        if (kph == 1) {
            __syncthreads();
            if (wc >= 2) {   // phase B: waves wc>=2 write h cols 128..255
#pragma unroll
                for (int nf = 0; nf < 4; ++nf) {
                    const int kA2 = ((nbase - 128) + nf*16 + khi*4) * 2;
#pragma unroll
                    for (int mf = 0; mf < 8; ++mf) {
                        const int m = wr*128 + mf*16 + l15;
                        *(bf16x4*)(hA + m*256 + (kA2 ^ ((m & 7) << 4))) = hreg[nf][mf];
                    }
                }
            }
            __syncthreads();
        }
#pragma unroll
        for (int ksl = 0; ksl < 2; ++ksl) {
#pragma unroll
            for (int kk = 0; kk < 2; ++kk) {
                const int kbH = (ksl*64 + kk*32 + khi*8) * 2;
                const int kbW = (kk*32 + khi*8) * 2;
                bf16x8 ah[4], bw[4];
#pragma unroll
                for (int mf2 = 0; mf2 < 4; ++mf2) {
                    const int m = m2b + mf2*16 + l15;
                    ah[mf2] = *(const bf16x8*)(hA + m*256 + (kbH ^ ((m & 7) << 4)));
                }
#pragma unroll
                for (int nf2 = 0; nf2 < 4; ++nf2) {
                    const int n = n2b + nf2*16 + l15;
                    bw[nf2] = *(const bf16x8*)(lds + 65536 + (kph*2 + ksl)*16384
                                               + n*128 + (kbW ^ ((n & 7) << 4)));
                }
#pragma unroll
                for (int nf2 = 0; nf2 < 4; ++nf2)
#pragma unroll
                    for (int mf2 = 0; mf2 < 4; ++mf2)
                        acc2[nf2][mf2] = __builtin_amdgcn_mfma_f32_16x16x32_bf16(
                            ah[mf2], bw[nf2], acc2[nf2][mf2], 0, 0, 0);
            }
        }
    }

    // ---- epilogue 2: + b2 + residual x.  T-MAJOR decode: t = m>>4, s = m&15.
#pragma unroll
    for (int nf2 = 0; nf2 < 4; ++nf2) {
        const int n2 = n2b + nf2*16 + l15;
        const float b2v = b2[n2];
#pragma unroll
        for (int mf2 = 0; mf2 < 4; ++mf2) {
            const int mb = m2b + mf2*16 + khi*4;
#pragma unroll
            for (int r = 0; r < 4; ++r) {
                const int m = mb + r;
                const int s = s0 + (m & 15);
                const int t = (m >> 4) & 15;
                const size_t o = ((size_t)(b*S_LEN + s))*D_DIM + t*TD + n2;
                out[o] = x[o] + acc2[nf2][mf2][r] + b2v;
            }
        }
    }
}

extern "C" void kernel_launch(void* const* d_in, const int* in_sizes, int n_in,
                              void* d_out, int out_size, void* d_ws, size_t ws_size,
                              hipStream_t stream) {
    const float* x     = (const float*)d_in[0];
    const float* gamma = (const float*)d_in[1];
    const float* beta  = (const float*)d_in[2];
    const float* Wq    = (const float*)d_in[3];
    const float* bq    = (const float*)d_in[4];
    const float* Wk    = (const float*)d_in[5];
    const float* bk    = (const float*)d_in[6];
    const float* W1    = (const float*)d_in[7];
    const float* b1    = (const float*)d_in[8];
    const float* W2    = (const float*)d_in[9];
    const float* b2    = (const float*)d_in[10];
    float* out = (float*)d_out;

    char* ws = (char*)d_ws;
    float*  partial  = (float*) ws;                   // 4,194,304 B [512][2048]
    float*  partial2 = (float*) (ws + 4194304);       //   524,288 B [64][2048]
    float*  qkbuf    = (float*) (ws + 4718592);       //    32,768 B
    int*    routes   = (int*)   (ws + 4751360);       //       512 B
    bf16_t* W1t      = (bf16_t*)(ws + 4751872);       //   327,680 B
    bf16_t* W2t      = (bf16_t*)(ws + 5079552);       //    65,536 B

    k_prep<<<768, 256, 0, stream>>>(W1, W2, W1t, W2t);
    k_stats<<<512, 256, 0, stream>>>(x, partial);
    k_red1<<<64, 256, 0, stream>>>(partial, partial2);
    k_qk<<<64, 256, 0, stream>>>(partial2, gamma, beta, Wq, bq, Wk, bk, qkbuf);
    k_score<<<1, 256, 0, stream>>>(qkbuf, routes);
    k_mlp<<<512, 512, 0, stream>>>(x, gamma, beta, W1t, W2t, b1, b2, routes, out);
}

// Round 12
// 121.499 us; speedup vs baseline: 1.1937x; 1.0400x over previous
//
#include <hip/hip_runtime.h>
#include <stdint.h>

#define S_LEN 4096
#define D_DIM 2048
#define NT 16
#define TD 128
#define KW 4
#define CTX 640
#define HID 256

typedef __bf16 bf16_t;
typedef __bf16 bf16x8 __attribute__((ext_vector_type(8)));
typedef __bf16 bf16x4 __attribute__((ext_vector_type(4)));
typedef float f32x4 __attribute__((ext_vector_type(4)));
typedef unsigned int u32;
typedef u32 __attribute__((address_space(1))) gu32;
typedef u32 __attribute__((address_space(3))) lu32;

__device__ __forceinline__ void gload_lds16(const void* g, void* l) {
    __builtin_amdgcn_global_load_lds((const gu32*)g, (lu32*)l, 16, 0, 0);
}

// ---------------- Kernel 1: row stats + tile-sum partials (no xn write).
__global__ __launch_bounds__(256) void k_stats(const float* __restrict__ x,
                                               float* __restrict__ partial)
{
    __shared__ float wsum[4][2048];
    const int tid = threadIdx.x, lane = tid & 63, w = tid >> 6;
    const int blk = blockIdx.x;
    float cs[8][4];
#pragma unroll
    for (int j = 0; j < 8; ++j) { cs[j][0]=0.f; cs[j][1]=0.f; cs[j][2]=0.f; cs[j][3]=0.f; }
#pragma unroll
    for (int i = 0; i < 4; ++i) {
        const int r = blk*16 + w*4 + i;
        const float4* xr = (const float4*)(x + (size_t)r * D_DIM);
        float4 v[8]; float s = 0.f, ss = 0.f;
#pragma unroll
        for (int j = 0; j < 8; ++j) {
            v[j] = xr[j*64 + lane];
            s  += v[j].x + v[j].y + v[j].z + v[j].w;
            ss += v[j].x*v[j].x + v[j].y*v[j].y + v[j].z*v[j].z + v[j].w*v[j].w;
        }
#pragma unroll
        for (int off = 32; off; off >>= 1) { s += __shfl_xor(s, off); ss += __shfl_xor(ss, off); }
        const float mean = s * (1.f/2048.f);
        const float var  = ss * (1.f/2048.f) - mean*mean;
        const float rstd = rsqrtf(var + 1e-5f);
#pragma unroll
        for (int j = 0; j < 8; ++j) {
            cs[j][0] += (v[j].x - mean)*rstd;
            cs[j][1] += (v[j].y - mean)*rstd;
            cs[j][2] += (v[j].z - mean)*rstd;
            cs[j][3] += (v[j].w - mean)*rstd;
        }
    }
#pragma unroll
    for (int j = 0; j < 8; ++j) {
        float4 t4; t4.x=cs[j][0]; t4.y=cs[j][1]; t4.z=cs[j][2]; t4.w=cs[j][3];
        *(float4*)&wsum[w][(j*64+lane)*4] = t4;
    }
    __syncthreads();
#pragma unroll
    for (int p = 0; p < 2; ++p) {
        const int c4 = p*256 + tid;
        float4 a0 = *(const float4*)&wsum[0][c4*4];
        float4 a1 = *(const float4*)&wsum[1][c4*4];
        float4 a2 = *(const float4*)&wsum[2][c4*4];
        float4 a3 = *(const float4*)&wsum[3][c4*4];
        float4 r4; r4.x=a0.x+a1.x+a2.x+a3.x; r4.y=a0.y+a1.y+a2.y+a3.y;
        r4.z=a0.z+a1.z+a2.z+a3.z; r4.w=a0.w+a1.w+a2.w+a3.w;
        *(float4*)(partial + (size_t)blk*D_DIM + c4*4) = r4;
    }
}

// ---------------- Kernel 2a: partial[512][2048] -> partial2[64][2048]
__global__ __launch_bounds__(256) void k_red1(const float* __restrict__ partial,
                                              float* __restrict__ partial2) {
    const int g = blockIdx.x, tid = threadIdx.x;
#pragma unroll
    for (int p = 0; p < 2; ++p) {
        const int c4 = p*256 + tid;
        float4 s = {0.f,0.f,0.f,0.f};
#pragma unroll
        for (int r = 0; r < 8; ++r) {
            float4 v = *(const float4*)(partial + ((size_t)(g*8+r))*2048 + c4*4);
            s.x+=v.x; s.y+=v.y; s.z+=v.z; s.w+=v.w;
        }
        *(float4*)(partial2 + (size_t)g*2048 + c4*4) = s;
    }
}

// ---------------- Kernel 3a: reduce partial2 (+gamma/beta) + q/k proj + l2norm
__global__ __launch_bounds__(256) void k_qk(const float* __restrict__ partial2,
        const float* __restrict__ gamma, const float* __restrict__ beta,
        const float* __restrict__ Wq, const float* __restrict__ bq,
        const float* __restrict__ Wk, const float* __restrict__ bk,
        float* __restrict__ qkbuf)
{
    __shared__ float red2[2][128];
    __shared__ float rrow[128];
    __shared__ float yrow[128];
    __shared__ float ssum[2];
    const int g = blockIdx.x;
    const int b = g >> 5, t = (g >> 1) & 15, which = g & 1;
    const float* W    = which ? Wk : Wq;
    const float* bias = which ? bk : bq;
    const int tid = threadIdx.x, lane = tid & 63, w = tid >> 6;
    {
        const int c = tid & 127, hh = tid >> 7;
        float s = 0.f;
#pragma unroll
        for (int r = 0; r < 16; ++r)
            s += partial2[(size_t)(b*32 + hh*16 + r)*2048 + t*128 + c];
        red2[hh][c] = s;
    }
    __syncthreads();
    if (tid < 128)
        rrow[tid] = gamma[t*128 + tid] * (red2[0][tid] + red2[1][tid]) * (1.f/4096.f)
                  + beta[t*128 + tid];
    __syncthreads();
    const int c0 = (lane & 15) * 8;
#pragma unroll
    for (int r = 0; r < 8; ++r) {
        const int d = r*16 + w*4 + (lane >> 4);
        const float4 w0 = *(const float4*)(W + d*128 + c0);
        const float4 w1 = *(const float4*)(W + d*128 + c0 + 4);
        float acc = w0.x*rrow[c0]   + w0.y*rrow[c0+1] + w0.z*rrow[c0+2] + w0.w*rrow[c0+3]
                  + w1.x*rrow[c0+4] + w1.y*rrow[c0+5] + w1.z*rrow[c0+6] + w1.w*rrow[c0+7];
#pragma unroll
        for (int off = 1; off <= 8; off <<= 1) acc += __shfl_xor(acc, off);
        if ((lane & 15) == 0) yrow[d] = acc + bias[d];
    }
    __syncthreads();
    if (tid < 128) {
        float v = yrow[tid];
        float sq = v * v;
#pragma unroll
        for (int off = 32; off; off >>= 1) sq += __shfl_xor(sq, off);
        if (lane == 0) ssum[tid >> 6] = sq;
    }
    __syncthreads();
    if (tid < 128) {
        const float rn = 1.f / fmaxf(sqrtf(ssum[0] + ssum[1]), 1e-12f);
        qkbuf[(which*32 + b*16 + t)*128 + tid] = yrow[tid] * rn;
    }
}

// ---------------- Kernel 3b: scores + top-4 -> routes [B][T][K]
__global__ __launch_bounds__(256) void k_score(const float* __restrict__ qkbuf,
                                               int* __restrict__ routes)
{
    __shared__ float qk_s[8192];
    __shared__ float sc[2][16][16];
    const int tid = threadIdx.x;
    for (int i = tid; i < 2048; i += 256)
        *(float4*)&qk_s[i*4] = *(const float4*)(qkbuf + i*4);
    __syncthreads();
#pragma unroll
    for (int p = 0; p < 2; ++p) {
        const int e = p*256 + tid;
        const int b = e >> 8, t = (e >> 4) & 15, u = e & 15;
        const float4* qr = (const float4*)&qk_s[(b*16 + t)*128];
        const float4* kr = (const float4*)&qk_s[(32 + b*16 + u)*128];
        float s = 0.f;
#pragma unroll
        for (int c = 0; c < 32; ++c) {
            float4 a = qr[c], bb = kr[c];
            s += a.x*bb.x + a.y*bb.y + a.z*bb.z + a.w*bb.w;
        }
        sc[b][t][u] = (u == t) ? -1e9f : s;
    }
    __syncthreads();
    if (tid < 32) {
        const int b = tid >> 4, t = tid & 15;
        unsigned taken = 0;
        for (int kk = 0; kk < 4; ++kk) {
            float bv = -3.0e38f; int bu = 0;
            for (int u = 0; u < 16; ++u) {
                if ((taken >> u) & 1u) continue;
                const float v = sc[b][t][u];
                if (v > bv) { bv = v; bu = u; }   // strict > = lax.top_k tie-break
            }
            taken |= (1u << bu);
            routes[(b*16 + t)*4 + kk] = bu;
        }
    }
}

// ---------------- Kernel 4: pre-tile + pre-swizzle W1/W2 into bf16 LDS images
// LDS slot L holds logical element at (byte L) ^ ((row&7)<<4)  [rows of 128B]
__global__ void k_prep(const float* __restrict__ W1, const float* __restrict__ W2,
                       bf16_t* __restrict__ W1t, bf16_t* __restrict__ W2t) {
    const int g = blockIdx.x * 256 + threadIdx.x;
    if (g < 10*256*64) {
        const int ks = g >> 14, rem = g & 16383, n = rem >> 6, kk = rem & 63;
        const int kkl = ((kk << 1) ^ ((n & 7) << 4)) >> 1;
        W1t[g] = (bf16_t)W1[n*CTX + ks*64 + kkl];
    } else if (g < 10*256*64 + 4*128*64) {
        const int gg = g - 10*256*64;
        const int ks = gg >> 13, rem = gg & 8191, n = rem >> 6, kk = rem & 63;
        const int kkl = ((kk << 1) ^ ((n & 7) << 4)) >> 1;
        W2t[gg] = (bf16_t)W2[n*HID + ks*64 + kkl];
    }
}

// ---------------- Kernel 5: fused LN + gather + MLP + residual.
// 512 blocks x 512 threads (8 waves). T-MAJOR output rows (m = t*16+s) as r11.
// GEMM1 is BARRIER-FREE: each wave stages ITS OWN 8KB W1 n-slice into a
// wave-private LDS region (waves w, w+4 duplicate — L2-cheap), synced purely by
// per-wave vmcnt/lgkmcnt. Per ks: vmcnt(0) -> read af0/af1+bfr0 -> lgkmcnt(0)
// (WAR seal) -> issue stage(ks+1) -> MFMA32 -> read bfr1 -> MFMA32. Waves
// desync freely: one wave's LDS storm overlaps siblings' MFMA storms (m114).
// LDS: xnL 64KB @0 (read-only in GEMM1); priv W1 [w] 8KB @64K+w*8K; srcT @128K.
// GEMM2: hA 64KB @0 (alias xnL), W2 64KB @64K — barriers only there (5 total).
__global__ __launch_bounds__(512, 1) void k_mlp(
    const float* __restrict__ x,
    const float* __restrict__ gamma, const float* __restrict__ beta,
    const bf16_t* __restrict__ W1t, const bf16_t* __restrict__ W2t,
    const float* __restrict__ b1, const float* __restrict__ b2,
    const int* __restrict__ routes, float* __restrict__ out)
{
    __shared__ char lds[131392];
    int* srcT = (int*)(lds + 131072);

    const int tid = threadIdx.x, lane = tid & 63, w = tid >> 6;
    const int blk = blockIdx.x;
    const int b  = blk >> 8;
    const int s0 = (blk & 255) * 16;

    const int wc = w & 3, wr = w >> 2;
    const int nbase = wc * 64;
    const int l15 = lane & 15;
    const int khi = lane >> 4;
    const int cswz = (l15 & 7) << 4;              // gather reader chunk-XOR
    char* priv = lds + 65536 + w*8192;            // wave-private W1 slice

    if (tid < 80) {
        const int t = tid / 5, j = tid % 5;
        srcT[tid] = (j == 0) ? t : routes[(b*NT + t)*KW + (j-1)];
    }

    // prologue: stage W1 slice(ks=0) — lands while LN runs
    {
        const bf16_t* w1g = W1t + wc*4096 + lane*8;
#pragma unroll
        for (int it = 0; it < 8; ++it)
            gload_lds16(w1g + it*512, priv + it*1024);
    }

    // ---- Stage 1: LayerNorm 16 rows -> xnL (bf16, tile-row swizzled) ----
#pragma unroll
    for (int i = 0; i < 2; ++i) {
        const int sl = w*2 + i;
        const float4* xr = (const float4*)(x + ((size_t)(b*S_LEN + s0 + sl))*D_DIM);
        float4 v[8]; float s = 0.f, ss = 0.f;
#pragma unroll
        for (int q = 0; q < 4; ++q) {
#pragma unroll
            for (int p = 0; p < 2; ++p) {
                float4 vv = xr[(q*64 + lane)*2 + p];
                v[q*2+p] = vv;
                s  += vv.x + vv.y + vv.z + vv.w;
                ss += vv.x*vv.x + vv.y*vv.y + vv.z*vv.z + vv.w*vv.w;
            }
        }
#pragma unroll
        for (int off = 32; off; off >>= 1) { s += __shfl_xor(s, off); ss += __shfl_xor(ss, off); }
        const float mean = s * (1.f/2048.f);
        const float var  = ss * (1.f/2048.f) - mean*mean;
        const float rstd = rsqrtf(var + 1e-5f);
        const float4* g4 = (const float4*)gamma;
        const float4* e4 = (const float4*)beta;
#pragma unroll
        for (int q = 0; q < 4; ++q) {
            const int gch = q*64 + lane;          // global 16B-chunk 0..255
            const float4 va = v[q*2], vb = v[q*2+1];
            const float4 ga = g4[gch*2], gb = g4[gch*2+1];
            const float4 ea = e4[gch*2], eb = e4[gch*2+1];
            bf16x8 o;
            o[0] = (bf16_t)((va.x - mean)*rstd*ga.x + ea.x);
            o[1] = (bf16_t)((va.y - mean)*rstd*ga.y + ea.y);
            o[2] = (bf16_t)((va.z - mean)*rstd*ga.z + ea.z);
            o[3] = (bf16_t)((va.w - mean)*rstd*ga.w + ea.w);
            o[4] = (bf16_t)((vb.x - mean)*rstd*gb.x + eb.x);
            o[5] = (bf16_t)((vb.y - mean)*rstd*gb.y + eb.y);
            o[6] = (bf16_t)((vb.z - mean)*rstd*gb.z + eb.z);
            o[7] = (bf16_t)((vb.w - mean)*rstd*gb.w + eb.w);
            const int u  = gch >> 4;              // source tile
            const int cw = gch & 15;              // chunk within tile
            *(bf16x8*)(lds + sl*4096 + u*256 + ((cw ^ (sl & 7)) << 4)) = o;
        }
    }
    __syncthreads();   // xnL + srcT visible to all waves

    f32x4 acc[4][8];
#pragma unroll
    for (int i = 0; i < 4; ++i)
#pragma unroll
        for (int j = 0; j < 8; ++j) acc[i][j] = (f32x4){0.f,0.f,0.f,0.f};

    // ---- GEMM1: barrier-free K-loop ----
    for (int ks = 0; ks < 10; ++ks) {
        asm volatile("s_waitcnt vmcnt(0)" ::: "memory");   // stage(ks) landed
        int us[8];
#pragma unroll
        for (int mf = 0; mf < 8; ++mf)
            us[mf] = srcT[(wr*8 + mf)*5 + (ks >> 1)];      // broadcast reads
        bf16x8 af0[4], af1[4], bfr[8];
#pragma unroll
        for (int nf = 0; nf < 4; ++nf) {
            const int n = nf*16 + l15;
            af0[nf] = *(const bf16x8*)(priv + n*128 + ((khi*16)      ^ ((n & 7) << 4)));
            af1[nf] = *(const bf16x8*)(priv + n*128 + ((64 + khi*16) ^ ((n & 7) << 4)));
        }
        {
            const int co = (((ks & 1)*8 + khi) << 4) ^ cswz;       // kk=0
#pragma unroll
            for (int mf = 0; mf < 8; ++mf)
                bfr[mf] = *(const bf16x8*)(lds + l15*4096 + us[mf]*256 + co);
        }
        asm volatile("s_waitcnt lgkmcnt(0)" ::: "memory"); // priv reads done (WAR)
        if (ks < 9) {                                      // stage(ks+1) -> priv
            const bf16_t* w1g = W1t + (ks + 1)*16384 + wc*4096 + lane*8;
#pragma unroll
            for (int it = 0; it < 8; ++it)
                gload_lds16(w1g + it*512, priv + it*1024);
        }
        __builtin_amdgcn_s_setprio(1);
#pragma unroll
        for (int nf = 0; nf < 4; ++nf)
#pragma unroll
            for (int mf = 0; mf < 8; ++mf)
                acc[nf][mf] = __builtin_amdgcn_mfma_f32_16x16x32_bf16(
                    af0[nf], bfr[mf], acc[nf][mf], 0, 0, 0);
        __builtin_amdgcn_s_setprio(0);
        {
            const int co = (((ks & 1)*8 + 4 + khi) << 4) ^ cswz;   // kk=1
#pragma unroll
            for (int mf = 0; mf < 8; ++mf)
                bfr[mf] = *(const bf16x8*)(lds + l15*4096 + us[mf]*256 + co);
        }
        __builtin_amdgcn_s_setprio(1);
#pragma unroll
        for (int nf = 0; nf < 4; ++nf)
#pragma unroll
            for (int mf = 0; mf < 8; ++mf)
                acc[nf][mf] = __builtin_amdgcn_mfma_f32_16x16x32_bf16(
                    af1[nf], bfr[mf], acc[nf][mf], 0, 0, 0);
        __builtin_amdgcn_s_setprio(0);
    }

    // ---- epilogue 1: bias + gelu -> packed bf16 regs (register-only) ----
    bf16x4 hreg[4][8];
#pragma unroll
    for (int nf = 0; nf < 4; ++nf) {
        const int k0 = nbase + nf*16 + khi*4;
        const float4 b1v = *(const float4*)(b1 + k0);
#pragma unroll
        for (int mf = 0; mf < 8; ++mf) {
#pragma unroll
            for (int r = 0; r < 4; ++r) {
                const float z = acc[nf][mf][r] + ((const float*)&b1v)[r];
                const float uu = z + 0.044715f * z * z * z;
                const float gl = z / (1.f + __expf(-1.5957691216f * uu));
                hreg[nf][mf][r] = (bf16_t)gl;
            }
        }
    }

    __syncthreads();   // ALL waves done reading xnL/priv before overwrite

    // stage ALL of W2 (64KB) into [64K,128K) — priv slices dead
#pragma unroll
    for (int it = 0; it < 8; ++it) {
        const int q = it*8 + w;
        gload_lds16(W2t + q*512 + lane*8, lds + 65536 + q*1024);
    }

    char* hA = lds;   // [256 m][128 k] bf16, 64KB (phased over hid-halves)

    // phase A: waves wc<2 write h cols 0..127
    if (wc < 2) {
#pragma unroll
        for (int nf = 0; nf < 4; ++nf) {
            const int kA2 = (nbase + nf*16 + khi*4) * 2;
#pragma unroll
            for (int mf = 0; mf < 8; ++mf) {
                const int m = wr*128 + mf*16 + l15;
                *(bf16x4*)(hA + m*256 + (kA2 ^ ((m & 7) << 4))) = hreg[nf][mf];
            }
        }
    }
    asm volatile("s_waitcnt vmcnt(0)" ::: "memory");
    __syncthreads();

    // ---- GEMM2: out = h @ W2^T, M=256 (wm), N=128 (wn), K=256 in 2 phases ----
    const int wn = w & 1, wm = w >> 1;
    const int n2b = wn*64, m2b = wm*64;
    f32x4 acc2[4][4];
#pragma unroll
    for (int i = 0; i < 4; ++i)
#pragma unroll
        for (int j = 0; j < 4; ++j) acc2[i][j] = (f32x4){0.f,0.f,0.f,0.f};

#pragma unroll
    for (int kph = 0; kph < 2; ++kph) {
        if (kph == 1) {
            __syncthreads();
            if (wc >= 2) {   // phase B: waves wc>=2 write h cols 128..255
#pragma unroll
                for (int nf = 0; nf < 4; ++nf) {
                    const int kA2 = ((nbase - 128) + nf*16 + khi*4) * 2;
#pragma unroll
                    for (int mf = 0; mf < 8; ++mf) {
                        const int m = wr*128 + mf*16 + l15;
                        *(bf16x4*)(hA + m*256 + (kA2 ^ ((m & 7) << 4))) = hreg[nf][mf];
                    }
                }
            }
            __syncthreads();
        }
#pragma unroll
        for (int ksl = 0; ksl < 2; ++ksl) {
#pragma unroll
            for (int kk = 0; kk < 2; ++kk) {
                const int kbH = (ksl*64 + kk*32 + khi*8) * 2;
                const int kbW = (kk*32 + khi*8) * 2;
                bf16x8 ah[4], bw[4];
#pragma unroll
                for (int mf2 = 0; mf2 < 4; ++mf2) {
                    const int m = m2b + mf2*16 + l15;
                    ah[mf2] = *(const bf16x8*)(hA + m*256 + (kbH ^ ((m & 7) << 4)));
                }
#pragma unroll
                for (int nf2 = 0; nf2 < 4; ++nf2) {
                    const int n = n2b + nf2*16 + l15;
                    bw[nf2] = *(const bf16x8*)(lds + 65536 + (kph*2 + ksl)*16384
                                               + n*128 + (kbW ^ ((n & 7) << 4)));
                }
#pragma unroll
                for (int nf2 = 0; nf2 < 4; ++nf2)
#pragma unroll
                    for (int mf2 = 0; mf2 < 4; ++mf2)
                        acc2[nf2][mf2] = __builtin_amdgcn_mfma_f32_16x16x32_bf16(
                            ah[mf2], bw[nf2], acc2[nf2][mf2], 0, 0, 0);
            }
        }
    }

    // ---- epilogue 2: + b2 + residual x.  T-MAJOR decode: t = m>>4, s = m&15.
#pragma unroll
    for (int nf2 = 0; nf2 < 4; ++nf2) {
        const int n2 = n2b + nf2*16 + l15;
        const float b2v = b2[n2];
#pragma unroll
        for (int mf2 = 0; mf2 < 4; ++mf2) {
            const int mb = m2b + mf2*16 + khi*4;
#pragma unroll
            for (int r = 0; r < 4; ++r) {
                const int m = mb + r;
                const int s = s0 + (m & 15);
                const int t = (m >> 4) & 15;
                const size_t o = ((size_t)(b*S_LEN + s))*D_DIM + t*TD + n2;
                out[o] = x[o] + acc2[nf2][mf2][r] + b2v;
            }
        }
    }
}

extern "C" void kernel_launch(void* const* d_in, const int* in_sizes, int n_in,
                              void* d_out, int out_size, void* d_ws, size_t ws_size,
                              hipStream_t stream) {
    const float* x     = (const float*)d_in[0];
    const float* gamma = (const float*)d_in[1];
    const float* beta  = (const float*)d_in[2];
    const float* Wq    = (const float*)d_in[3];
    const float* bq    = (const float*)d_in[4];
    const float* Wk    = (const float*)d_in[5];
    const float* bk    = (const float*)d_in[6];
    const float* W1    = (const float*)d_in[7];
    const float* b1    = (const float*)d_in[8];
    const float* W2    = (const float*)d_in[9];
    const float* b2    = (const float*)d_in[10];
    float* out = (float*)d_out;

    char* ws = (char*)d_ws;
    float*  partial  = (float*) ws;                   // 4,194,304 B [512][2048]
    float*  partial2 = (float*) (ws + 4194304);       //   524,288 B [64][2048]
    float*  qkbuf    = (float*) (ws + 4718592);       //    32,768 B
    int*    routes   = (int*)   (ws + 4751360);       //       512 B
    bf16_t* W1t      = (bf16_t*)(ws + 4751872);       //   327,680 B
    bf16_t* W2t      = (bf16_t*)(ws + 5079552);       //    65,536 B

    k_prep<<<768, 256, 0, stream>>>(W1, W2, W1t, W2t);
    k_stats<<<512, 256, 0, stream>>>(x, partial);
    k_red1<<<64, 256, 0, stream>>>(partial, partial2);
    k_qk<<<64, 256, 0, stream>>>(partial2, gamma, beta, Wq, bq, Wk, bk, qkbuf);
    k_score<<<1, 256, 0, stream>>>(qkbuf, routes);
    k_mlp<<<512, 512, 0, stream>>>(x, gamma, beta, W1t, W2t, b1, b2, routes, out);
}

// Round 14
// 115.819 us; speedup vs baseline: 1.2522x; 1.0490x over previous
//
#include <hip/hip_runtime.h>
#include <stdint.h>

#define S_LEN 4096
#define D_DIM 2048
#define NT 16
#define TD 128
#define KW 4
#define CTX 640
#define HID 256

typedef __bf16 bf16_t;
typedef __bf16 bf16x8 __attribute__((ext_vector_type(8)));
typedef __bf16 bf16x4 __attribute__((ext_vector_type(4)));
typedef float f32x4 __attribute__((ext_vector_type(4)));
typedef unsigned int u32;
typedef u32 __attribute__((address_space(1))) gu32;
typedef u32 __attribute__((address_space(3))) lu32;

__device__ __forceinline__ void gload_lds16(const void* g, void* l) {
    __builtin_amdgcn_global_load_lds((const gu32*)g, (lu32*)l, 16, 0, 0);
}

// ---------------- Kernel 1 (merged): blocks 0..511 = row stats + tile-sum
// partials; blocks 512..1279 = W1/W2 pre-tile/pre-swizzle.
__global__ __launch_bounds__(256) void k_pre(const float* __restrict__ x,
        const float* __restrict__ W1, const float* __restrict__ W2,
        float* __restrict__ partial, bf16_t* __restrict__ W1t, bf16_t* __restrict__ W2t)
{
    if (blockIdx.x >= 512) {   // ---- prep part ----
        const int g = (blockIdx.x - 512) * 256 + threadIdx.x;
        if (g < 10*256*64) {
            const int ks = g >> 14, rem = g & 16383, n = rem >> 6, kk = rem & 63;
            const int kkl = ((kk << 1) ^ ((n & 7) << 4)) >> 1;
            W1t[g] = (bf16_t)W1[n*CTX + ks*64 + kkl];
        } else if (g < 10*256*64 + 4*128*64) {
            const int gg = g - 10*256*64;
            const int ks = gg >> 13, rem = gg & 8191, n = rem >> 6, kk = rem & 63;
            const int kkl = ((kk << 1) ^ ((n & 7) << 4)) >> 1;
            W2t[gg] = (bf16_t)W2[n*HID + ks*64 + kkl];
        }
        return;
    }
    // ---- stats part ----
    __shared__ float wsum[4][2048];
    const int tid = threadIdx.x, lane = tid & 63, w = tid >> 6;
    const int blk = blockIdx.x;
    float cs[8][4];
#pragma unroll
    for (int j = 0; j < 8; ++j) { cs[j][0]=0.f; cs[j][1]=0.f; cs[j][2]=0.f; cs[j][3]=0.f; }
#pragma unroll
    for (int i = 0; i < 4; ++i) {
        const int r = blk*16 + w*4 + i;
        const float4* xr = (const float4*)(x + (size_t)r * D_DIM);
        float4 v[8]; float s = 0.f, ss = 0.f;
#pragma unroll
        for (int j = 0; j < 8; ++j) {
            v[j] = xr[j*64 + lane];
            s  += v[j].x + v[j].y + v[j].z + v[j].w;
            ss += v[j].x*v[j].x + v[j].y*v[j].y + v[j].z*v[j].z + v[j].w*v[j].w;
        }
#pragma unroll
        for (int off = 32; off; off >>= 1) { s += __shfl_xor(s, off); ss += __shfl_xor(ss, off); }
        const float mean = s * (1.f/2048.f);
        const float var  = ss * (1.f/2048.f) - mean*mean;
        const float rstd = rsqrtf(var + 1e-5f);
#pragma unroll
        for (int j = 0; j < 8; ++j) {
            cs[j][0] += (v[j].x - mean)*rstd;
            cs[j][1] += (v[j].y - mean)*rstd;
            cs[j][2] += (v[j].z - mean)*rstd;
            cs[j][3] += (v[j].w - mean)*rstd;
        }
    }
#pragma unroll
    for (int j = 0; j < 8; ++j) {
        float4 t4; t4.x=cs[j][0]; t4.y=cs[j][1]; t4.z=cs[j][2]; t4.w=cs[j][3];
        *(float4*)&wsum[w][(j*64+lane)*4] = t4;
    }
    __syncthreads();
#pragma unroll
    for (int p = 0; p < 2; ++p) {
        const int c4 = p*256 + tid;
        float4 a0 = *(const float4*)&wsum[0][c4*4];
        float4 a1 = *(const float4*)&wsum[1][c4*4];
        float4 a2 = *(const float4*)&wsum[2][c4*4];
        float4 a3 = *(const float4*)&wsum[3][c4*4];
        float4 r4; r4.x=a0.x+a1.x+a2.x+a3.x; r4.y=a0.y+a1.y+a2.y+a3.y;
        r4.z=a0.z+a1.z+a2.z+a3.z; r4.w=a0.w+a1.w+a2.w+a3.w;
        *(float4*)(partial + (size_t)blk*D_DIM + c4*4) = r4;
    }
}

// ---------------- Kernel 2a: partial[512][2048] -> partial2[64][2048]
__global__ __launch_bounds__(256) void k_red1(const float* __restrict__ partial,
                                              float* __restrict__ partial2) {
    const int g = blockIdx.x, tid = threadIdx.x;
#pragma unroll
    for (int p = 0; p < 2; ++p) {
        const int c4 = p*256 + tid;
        float4 s = {0.f,0.f,0.f,0.f};
#pragma unroll
        for (int r = 0; r < 8; ++r) {
            float4 v = *(const float4*)(partial + ((size_t)(g*8+r))*2048 + c4*4);
            s.x+=v.x; s.y+=v.y; s.z+=v.z; s.w+=v.w;
        }
        *(float4*)(partial2 + (size_t)g*2048 + c4*4) = s;
    }
}

// ---------------- Kernel 3a: reduce partial2 (+gamma/beta) + q/k proj + l2norm
__global__ __launch_bounds__(256) void k_qk(const float* __restrict__ partial2,
        const float* __restrict__ gamma, const float* __restrict__ beta,
        const float* __restrict__ Wq, const float* __restrict__ bq,
        const float* __restrict__ Wk, const float* __restrict__ bk,
        float* __restrict__ qkbuf)
{
    __shared__ float red2[2][128];
    __shared__ float rrow[128];
    __shared__ float yrow[128];
    __shared__ float ssum[2];
    const int g = blockIdx.x;
    const int b = g >> 5, t = (g >> 1) & 15, which = g & 1;
    const float* W    = which ? Wk : Wq;
    const float* bias = which ? bk : bq;
    const int tid = threadIdx.x, lane = tid & 63, w = tid >> 6;
    {
        const int c = tid & 127, hh = tid >> 7;
        float s = 0.f;
#pragma unroll
        for (int r = 0; r < 16; ++r)
            s += partial2[(size_t)(b*32 + hh*16 + r)*2048 + t*128 + c];
        red2[hh][c] = s;
    }
    __syncthreads();
    if (tid < 128)
        rrow[tid] = gamma[t*128 + tid] * (red2[0][tid] + red2[1][tid]) * (1.f/4096.f)
                  + beta[t*128 + tid];
    __syncthreads();
    const int c0 = (lane & 15) * 8;
#pragma unroll
    for (int r = 0; r < 8; ++r) {
        const int d = r*16 + w*4 + (lane >> 4);
        const float4 w0 = *(const float4*)(W + d*128 + c0);
        const float4 w1 = *(const float4*)(W + d*128 + c0 + 4);
        float acc = w0.x*rrow[c0]   + w0.y*rrow[c0+1] + w0.z*rrow[c0+2] + w0.w*rrow[c0+3]
                  + w1.x*rrow[c0+4] + w1.y*rrow[c0+5] + w1.z*rrow[c0+6] + w1.w*rrow[c0+7];
#pragma unroll
        for (int off = 1; off <= 8; off <<= 1) acc += __shfl_xor(acc, off);
        if ((lane & 15) == 0) yrow[d] = acc + bias[d];
    }
    __syncthreads();
    if (tid < 128) {
        float v = yrow[tid];
        float sq = v * v;
#pragma unroll
        for (int off = 32; off; off >>= 1) sq += __shfl_xor(sq, off);
        if (lane == 0) ssum[tid >> 6] = sq;
    }
    __syncthreads();
    if (tid < 128) {
        const float rn = 1.f / fmaxf(sqrtf(ssum[0] + ssum[1]), 1e-12f);
        qkbuf[(which*32 + b*16 + t)*128 + tid] = yrow[tid] * rn;
    }
}

// ---------------- Kernel 3b: scores + top-4 -> routes [B][T][K]
__global__ __launch_bounds__(256) void k_score(const float* __restrict__ qkbuf,
                                               int* __restrict__ routes)
{
    __shared__ float qk_s[8192];
    __shared__ float sc[2][16][16];
    const int tid = threadIdx.x;
    for (int i = tid; i < 2048; i += 256)
        *(float4*)&qk_s[i*4] = *(const float4*)(qkbuf + i*4);
    __syncthreads();
#pragma unroll
    for (int p = 0; p < 2; ++p) {
        const int e = p*256 + tid;
        const int b = e >> 8, t = (e >> 4) & 15, u = e & 15;
        const float4* qr = (const float4*)&qk_s[(b*16 + t)*128];
        const float4* kr = (const float4*)&qk_s[(32 + b*16 + u)*128];
        float s = 0.f;
#pragma unroll
        for (int c = 0; c < 32; ++c) {
            float4 a = qr[c], bb = kr[c];
            s += a.x*bb.x + a.y*bb.y + a.z*bb.z + a.w*bb.w;
        }
        sc[b][t][u] = (u == t) ? -1e9f : s;
    }
    __syncthreads();
    if (tid < 32) {
        const int b = tid >> 4, t = tid & 15;
        unsigned taken = 0;
        for (int kk = 0; kk < 4; ++kk) {
            float bv = -3.0e38f; int bu = 0;
            for (int u = 0; u < 16; ++u) {
                if ((taken >> u) & 1u) continue;
                const float v = sc[b][t][u];
                if (v > bv) { bv = v; bu = u; }   // strict > = lax.top_k tie-break
            }
            taken |= (1u << bu);
            routes[(b*16 + t)*4 + kk] = bu;
        }
    }
}

// ---------------- Kernel 5: fused LN + gather + MLP + residual.
// 1024 blocks x 256 threads (4 waves) — round-6 geometry (best measured k_mlp,
// 83.5us) + fused LN / resident xnL (rounds 10-12).
// BM=128 rows, T-MAJOR: m = t*8 + s  (t = m>>3, s = m&7).
// LDS (64.5KB -> 2 blocks/CU): xnL [8 sl][16 u][16 ch] 32KB @0 (chunk stored
// at cw^sl -> conflict-free gather reads); W1 single-buf 32KB @32K; srcT @64K.
// GEMM2 aliases: hL 32KB @0, w2L 16KB @32K (round-6 verbatim).
// All cross-wave staged buffers follow stage -> vmcnt(0) -> __syncthreads ->
// read (round-13 race fixed: no reads-before-barrier on staged buffers).
__global__ __launch_bounds__(256, 2) void k_mlp(
    const float* __restrict__ x,
    const float* __restrict__ gamma, const float* __restrict__ beta,
    const bf16_t* __restrict__ W1t, const bf16_t* __restrict__ W2t,
    const float* __restrict__ b1, const float* __restrict__ b2,
    const int* __restrict__ routes, float* __restrict__ out)
{
    __shared__ char lds[65856];
    int* srcT = (int*)(lds + 65536);
    char* xnL = lds;                 // 32KB  (GEMM1, resident)
    char* w1L = lds + 32768;         // 32KB  (GEMM1, staged per ks)
    char* hL  = lds;                 // 32KB  (GEMM2, aliases xnL)
    char* w2L = lds + 32768;         // 16KB  (GEMM2, aliases w1L)

    const int tid = threadIdx.x, lane = tid & 63, w = tid >> 6;
    const int blk = blockIdx.x;
    const int b  = blk >> 9;
    const int s0 = (blk & 511) * 8;

    const int l15 = lane & 15;
    const int khi = lane >> 4;          // 0..3
    const int sl7 = l15 & 7;            // s-row of this lane's fragment element
    const int thi = l15 >> 3;           // tile-half selector within fragment

    if (tid < 80) {
        const int t = tid / 5, j = tid % 5;
        srcT[tid] = (j == 0) ? t : routes[(b*NT + t)*KW + (j-1)];
    }

    // prologue: stage W1(0) -> w1L (lands while LN runs)
    {
        const bf16_t* w1g = W1t + lane*8;
#pragma unroll
        for (int it = 0; it < 8; ++it) {
            const int q = it*4 + w;
            gload_lds16(w1g + q*512, w1L + q*1024);
        }
    }

    // ---- Stage 1: LayerNorm 8 rows (2/wave) -> xnL (bf16, swizzled) ----
#pragma unroll
    for (int i = 0; i < 2; ++i) {
        const int sl = w*2 + i;
        const float4* xr = (const float4*)(x + ((size_t)(b*S_LEN + s0 + sl))*D_DIM);
        float4 v[8]; float s = 0.f, ss = 0.f;
#pragma unroll
        for (int q = 0; q < 4; ++q) {
#pragma unroll
            for (int p = 0; p < 2; ++p) {
                float4 vv = xr[(q*64 + lane)*2 + p];
                v[q*2+p] = vv;
                s  += vv.x + vv.y + vv.z + vv.w;
                ss += vv.x*vv.x + vv.y*vv.y + vv.z*vv.z + vv.w*vv.w;
            }
        }
#pragma unroll
        for (int off = 32; off; off >>= 1) { s += __shfl_xor(s, off); ss += __shfl_xor(ss, off); }
        const float mean = s * (1.f/2048.f);
        const float var  = ss * (1.f/2048.f) - mean*mean;
        const float rstd = rsqrtf(var + 1e-5f);
        const float4* g4 = (const float4*)gamma;
        const float4* e4 = (const float4*)beta;
#pragma unroll
        for (int q = 0; q < 4; ++q) {
            const int gch = q*64 + lane;          // global 16B-chunk 0..255
            const float4 va = v[q*2], vb = v[q*2+1];
            const float4 ga = g4[gch*2], gb = g4[gch*2+1];
            const float4 ea = e4[gch*2], eb = e4[gch*2+1];
            bf16x8 o;
            o[0] = (bf16_t)((va.x - mean)*rstd*ga.x + ea.x);
            o[1] = (bf16_t)((va.y - mean)*rstd*ga.y + ea.y);
            o[2] = (bf16_t)((va.z - mean)*rstd*ga.z + ea.z);
            o[3] = (bf16_t)((va.w - mean)*rstd*ga.w + ea.w);
            o[4] = (bf16_t)((vb.x - mean)*rstd*gb.x + eb.x);
            o[5] = (bf16_t)((vb.y - mean)*rstd*gb.y + eb.y);
            o[6] = (bf16_t)((vb.z - mean)*rstd*gb.z + eb.z);
            o[7] = (bf16_t)((vb.w - mean)*rstd*gb.w + eb.w);
            const int u  = gch >> 4;
            const int cw = gch & 15;
            *(bf16x8*)(xnL + sl*4096 + u*256 + ((cw ^ sl) << 4)) = o;
        }
    }

    const int nbase = w * 64;
    f32x4 acc[4][8];
#pragma unroll
    for (int i = 0; i < 4; ++i)
#pragma unroll
        for (int j = 0; j < 8; ++j) acc[i][j] = (f32x4){0.f,0.f,0.f,0.f};

    // ---- GEMM1: resident-A, staged-W1, round-6 sync discipline ----
    for (int ks = 0; ks < 10; ++ks) {
        asm volatile("s_waitcnt vmcnt(0)" ::: "memory");  // own W1 chunks landed
        __syncthreads();                                   // ALL chunks (+xnL at ks=0)

        int us[8];
#pragma unroll
        for (int mf = 0; mf < 8; ++mf)
            us[mf] = srcT[(mf*2 + thi)*5 + (ks >> 1)];

#pragma unroll
        for (int kk = 0; kk < 2; ++kk) {
            const int kb = kk*64 + khi*16;                 // W1 byte offset in row
            const int co = ((((ks & 1)*8 + kk*4 + khi) ^ sl7) << 4);
            bf16x8 af[4], bfr[8];
#pragma unroll
            for (int nf = 0; nf < 4; ++nf) {
                const int n = nbase + nf*16 + l15;
                af[nf] = *(const bf16x8*)(w1L + n*128 + (kb ^ ((n & 7) << 4)));
            }
#pragma unroll
            for (int mf = 0; mf < 8; ++mf)
                bfr[mf] = *(const bf16x8*)(xnL + sl7*4096 + us[mf]*256 + co);
#pragma unroll
            for (int nf = 0; nf < 4; ++nf)
#pragma unroll
                for (int mf = 0; mf < 8; ++mf)
                    acc[nf][mf] = __builtin_amdgcn_mfma_f32_16x16x32_bf16(
                        af[nf], bfr[mf], acc[nf][mf], 0, 0, 0);
        }
        __syncthreads();     // full drain: all reads of w1L done (WAR seal)
        if (ks < 9) {        // stage W1(ks+1) -> w1L
            const bf16_t* w1g = W1t + (ks + 1)*16384 + lane*8;
#pragma unroll
            for (int it = 0; it < 8; ++it) {
                const int q = it*4 + w;
                gload_lds16(w1g + q*512, w1L + q*1024);
            }
        }
    }

    // ---- epilogue 1: bias + gelu -> packed bf16 regs ----
    bf16x4 hreg[4][8];
#pragma unroll
    for (int nf = 0; nf < 4; ++nf) {
        const int k0 = nbase + nf*16 + khi*4;
        const float4 b1v = *(const float4*)(b1 + k0);
#pragma unroll
        for (int mf = 0; mf < 8; ++mf) {
#pragma unroll
            for (int r = 0; r < 4; ++r) {
                const float z = acc[nf][mf][r] + ((const float*)&b1v)[r];
                const float uu = z + 0.044715f * z * z * z;
                const float gl = z / (1.f + __expf(-1.5957691216f * uu));
                hreg[nf][mf][r] = (bf16_t)gl;
            }
        }
    }

    // phase A: waves 0,1 write h cols 0..127 into hL (xnL dead after last sync)
    const int colb = (nbase & 127) + khi*4;
    if (w < 2) {
#pragma unroll
        for (int nf = 0; nf < 4; ++nf) {
            const int cb2 = (colb + nf*16) * 2;
#pragma unroll
            for (int mf = 0; mf < 8; ++mf) {
                const int m = mf*16 + l15;
                *(bf16x4*)(hL + m*256 + (cb2 ^ ((m & 7) << 4))) = hreg[nf][mf];
            }
        }
    }

    // ---- GEMM2: out = h @ W2^T, K=256 in 4 ks2 of 64 (round-6 verbatim) ----
    f32x4 acc2[2][8];
#pragma unroll
    for (int i = 0; i < 2; ++i)
#pragma unroll
        for (int j = 0; j < 8; ++j) acc2[i][j] = (f32x4){0.f,0.f,0.f,0.f};

    for (int ks2 = 0; ks2 < 4; ++ks2) {
        if (ks2 == 2) {
            if (w >= 2) {   // phase B: waves 2,3 write h cols 128..255
#pragma unroll
                for (int nf = 0; nf < 4; ++nf) {
                    const int cb2 = (colb + nf*16) * 2;
#pragma unroll
                    for (int mf = 0; mf < 8; ++mf) {
                        const int m = mf*16 + l15;
                        *(bf16x4*)(hL + m*256 + (cb2 ^ ((m & 7) << 4))) = hreg[nf][mf];
                    }
                }
            }
            __syncthreads();
        }
        const bf16_t* w2g = W2t + ks2*8192 + lane*8;
#pragma unroll
        for (int it = 0; it < 4; ++it) {
            const int q = it*4 + w;
            gload_lds16(w2g + q*512, w2L + q*1024);
        }
        asm volatile("s_waitcnt vmcnt(0)" ::: "memory");
        __syncthreads();
#pragma unroll
        for (int kk = 0; kk < 2; ++kk) {
            const int kbW = (kk*32 + khi*8) * 2;
            const int kbH = (((ks2 & 1) * 64) + kk*32 + khi*8) * 2;
            bf16x8 ah[8], bw2[2];
#pragma unroll
            for (int mf = 0; mf < 8; ++mf) {
                const int m = mf*16 + l15;
                ah[mf] = *(const bf16x8*)(hL + m*256 + (kbH ^ ((m & 7) << 4)));
            }
#pragma unroll
            for (int nf = 0; nf < 2; ++nf) {
                const int n2 = w*32 + nf*16 + l15;
                bw2[nf] = *(const bf16x8*)(w2L + n2*128 + (kbW ^ ((n2 & 7) << 4)));
            }
#pragma unroll
            for (int nf = 0; nf < 2; ++nf)
#pragma unroll
                for (int mf = 0; mf < 8; ++mf)
                    acc2[nf][mf] = __builtin_amdgcn_mfma_f32_16x16x32_bf16(
                        ah[mf], bw2[nf], acc2[nf][mf], 0, 0, 0);
        }
        __syncthreads();
    }

    // ---- epilogue 2: + b2 + residual x.  T-MAJOR decode: t = m>>3, s = m&7.
#pragma unroll
    for (int nf = 0; nf < 2; ++nf) {
        const int n2 = w*32 + nf*16 + l15;
        const float b2v = b2[n2];
#pragma unroll
        for (int mf = 0; mf < 8; ++mf) {
            const int mb = mf*16 + khi*4;
#pragma unroll
            for (int r = 0; r < 4; ++r) {
                const int m = mb + r;
                const int s = s0 + (m & 7);
                const int t = m >> 3;
                const size_t o = ((size_t)(b*S_LEN + s))*D_DIM + t*TD + n2;
                out[o] = x[o] + acc2[nf][mf][r] + b2v;
            }
        }
    }
}

extern "C" void kernel_launch(void* const* d_in, const int* in_sizes, int n_in,
                              void* d_out, int out_size, void* d_ws, size_t ws_size,
                              hipStream_t stream) {
    const float* x     = (const float*)d_in[0];
    const float* gamma = (const float*)d_in[1];
    const float* beta  = (const float*)d_in[2];
    const float* Wq    = (const float*)d_in[3];
    const float* bq    = (const float*)d_in[4];
    const float* Wk    = (const float*)d_in[5];
    const float* bk    = (const float*)d_in[6];
    const float* W1    = (const float*)d_in[7];
    const float* b1    = (const float*)d_in[8];
    const float* W2    = (const float*)d_in[9];
    const float* b2    = (const float*)d_in[10];
    float* out = (float*)d_out;

    char* ws = (char*)d_ws;
    float*  partial  = (float*) ws;                   // 4,194,304 B [512][2048]
    float*  partial2 = (float*) (ws + 4194304);       //   524,288 B [64][2048]
    float*  qkbuf    = (float*) (ws + 4718592);       //    32,768 B
    int*    routes   = (int*)   (ws + 4751360);       //       512 B
    bf16_t* W1t      = (bf16_t*)(ws + 4751872);       //   327,680 B
    bf16_t* W2t      = (bf16_t*)(ws + 5079552);       //    65,536 B

    k_pre<<<1280, 256, 0, stream>>>(x, W1, W2, partial, W1t, W2t);
    k_red1<<<64, 256, 0, stream>>>(partial, partial2);
    k_qk<<<64, 256, 0, stream>>>(partial2, gamma, beta, Wq, bq, Wk, bk, qkbuf);
    k_score<<<1, 256, 0, stream>>>(qkbuf, routes);
    k_mlp<<<1024, 256, 0, stream>>>(x, gamma, beta, W1t, W2t, b1, b2, routes, out);
}